// Round 7
// baseline (237.135 us; speedup 1.0000x reference)
//
#include <hip/hip_runtime.h>

#define N_SAMPLES 4096
#define D_IN      128
#define R_RULES   256
#define O_OUT     64
#define KPAD      136
#define NG16      16     // 16 rule-groups of 16 rules (K=16 per MFMA)
#define CP3_I     144    // padded i-slots per group in Cp3

typedef _Float16 f16;
typedef _Float16 f16x2 __attribute__((ext_vector_type(2)));
typedef _Float16 f16x4 __attribute__((ext_vector_type(4)));
typedef _Float16 f16x8 __attribute__((ext_vector_type(8)));
typedef float    f32x4 __attribute__((ext_vector_type(4)));
typedef float    f32x16 __attribute__((ext_vector_type(16)));

// ---------------------------------------------------------------------------
// Kernel 1 (unchanged from R6): fused prep -> Cp3 (32x32 B-fragment layout)
// and Bext (Markidis split).
// ---------------------------------------------------------------------------
__global__ __launch_bounds__(256) void anfis_prep_all(
    const float* __restrict__ coeffs, const float* __restrict__ centers,
    const float* __restrict__ sigmas, f16* __restrict__ Cp3,
    f16* __restrict__ Bext) {
  __shared__ alignas(16) f16 T[64 * 32];
  __shared__ float red[4];
  const int bid = blockIdx.x;
  const int tid = threadIdx.x;

  if (bid < 1088) {
    const int g8 = bid / 136;
    const int i = bid - g8 * 136;
    const int rg = tid & 31;
    const int jb = tid >> 5;
    if (i < 129) {
      const float* src = coeffs + ((size_t)(g8 * 32 + rg) * 129 + i) * 64 + jb * 8;
      float4 a = reinterpret_cast<const float4*>(src)[0];
      float4 b = reinterpret_cast<const float4*>(src)[1];
      T[(jb * 8 + 0) * 32 + rg] = (f16)a.x;
      T[(jb * 8 + 1) * 32 + rg] = (f16)a.y;
      T[(jb * 8 + 2) * 32 + rg] = (f16)a.z;
      T[(jb * 8 + 3) * 32 + rg] = (f16)a.w;
      T[(jb * 8 + 4) * 32 + rg] = (f16)b.x;
      T[(jb * 8 + 5) * 32 + rg] = (f16)b.y;
      T[(jb * 8 + 6) * 32 + rg] = (f16)b.z;
      T[(jb * 8 + 7) * 32 + rg] = (f16)b.w;
    } else {
#pragma unroll
      for (int q = 0; q < 8; ++q) T[(jb * 8 + q) * 32 + rg] = (f16)0.0f;
    }
    __syncthreads();
    const int j = tid >> 2, oc = tid & 3;
    const int g16 = g8 * 2 + (oc >> 1), rh = oc & 1;
    const int jh = j >> 5, jl = j & 31;
    f16x8* dst3 = reinterpret_cast<f16x8*>(Cp3);
    dst3[(((size_t)g16 * CP3_I + i) * 2 + jh) * 64 + rh * 32 + jl] =
        *reinterpret_cast<const f16x8*>(&T[j * 32 + oc * 8]);
  } else {
    const int sub = tid >> 7;
    const int d = tid & 127;
    const int r = ((bid - 1088) << 1) + sub;
    const float c = centers[(size_t)r * 128 + d];
    const float s = sigmas[(size_t)r * 128 + d];
    const float iv = 0.5f / (s * s);
    const float b1 = -iv;
    const float b2 = 2.0f * c * iv;
    f16 b1h = (f16)b1; f16 b1l = (f16)(b1 - (float)b1h);
    f16 b2h = (f16)b2; f16 b2l = (f16)(b2 - (float)b2h);
    auto put = [&](int k, f16 v) {
      Bext[((size_t)(k >> 3) * 256 + r) * 8 + (k & 7)] = v;
    };
    put(d, b1h);
    put(128 + d, b1l);
    put(256 + d, b1h);
    put(384 + d, b2h);
    put(512 + d, b2l);
    put(640 + d, b2h);
    float p = -c * c * iv;
#pragma unroll
    for (int off = 32; off; off >>= 1) p += __shfl_xor(p, off, 64);
    if ((tid & 63) == 0) red[tid >> 6] = p;
    __syncthreads();
    if (d < 30) put(770 + d, (f16)0.0f);
    if (d == 0) {
      float k2 = red[sub * 2] + red[sub * 2 + 1];
      f16 h = (f16)k2; f16 l = (f16)(k2 - (float)h);
      put(768, h);
      put(769, l);
    }
  }
}

// ---------------------------------------------------------------------------
// Kernel 2 (unchanged): strengths + normalization fused.
// ---------------------------------------------------------------------------
__global__ __launch_bounds__(512) void anfis_s16n(
    const float* __restrict__ X, const f16* __restrict__ Bext,
    f16* __restrict__ P) {
  __shared__ alignas(16) f16 Xq[16 * 512];
  __shared__ float rowsum[16][8];
  const int tid = threadIdx.x;
  const int m0 = blockIdx.x * 16;
  const int w = tid >> 6, lane = tid & 63;
  const int lm = lane & 15, quad = lane >> 4;

  if (tid < 256) {
    int m = tid >> 4, oct = tid & 15;
    const float* src = X + (size_t)(m0 + m) * 128 + oct * 8;
    float4 a = reinterpret_cast<const float4*>(src)[0];
    float4 b = reinterpret_cast<const float4*>(src)[1];
    float xs[8] = {a.x, a.y, a.z, a.w, b.x, b.y, b.z, b.w};
    f16x8 vh, vl, v2h, v2l;
#pragma unroll
    for (int q = 0; q < 8; ++q) {
      float x = xs[q];
      f16 h = (f16)x;   f16 l = (f16)(x - (float)h);
      float x2 = x * x;
      f16 h2 = (f16)x2; f16 l2 = (f16)(x2 - (float)h2);
      vh[q] = h; vl[q] = l; v2h[q] = h2; v2l[q] = l2;
    }
    f16x8* row = reinterpret_cast<f16x8*>(&Xq[m * 512]);
    int sw = m & 7;
    row[(0 * 16 + oct) ^ sw] = v2h;
    row[(1 * 16 + oct) ^ sw] = v2l;
    row[(2 * 16 + oct) ^ sw] = vh;
    row[(3 * 16 + oct) ^ sw] = vl;
  }
  __syncthreads();

  f32x4 acc[2] = {};
  const f16x8* arow = reinterpret_cast<const f16x8*>(&Xq[lm * 512]);
  const int asw = lm & 7;
  const int col0 = w * 32 + lm;

#pragma unroll
  for (int t = 0; t < 24; ++t) {
    const int seg = t >> 2;
    const int plane = (seg < 2) ? 0 : (seg == 2) ? 1 : (seg < 5) ? 2 : 3;
    const int o = t * 4 + quad;
    f16x8 av = arow[(plane * 16 + (o & 15)) ^ asw];
    const f16* bp = Bext + ((size_t)o * 256 + col0) * 8;
    f16x8 b0 = *reinterpret_cast<const f16x8*>(bp);
    f16x8 b1 = *reinterpret_cast<const f16x8*>(bp + 16 * 8);
    acc[0] = __builtin_amdgcn_mfma_f32_16x16x32_f16(av, b0, acc[0], 0, 0, 0);
    acc[1] = __builtin_amdgcn_mfma_f32_16x16x32_f16(av, b1, acc[1], 0, 0, 0);
  }
  {
    f16x8 av = {};
    if (quad == 0) { av[0] = (f16)1.0f; av[1] = (f16)1.0f; }
    const int o = 96 + quad;
    const f16* bp = Bext + ((size_t)o * 256 + col0) * 8;
    f16x8 b0 = *reinterpret_cast<const f16x8*>(bp);
    f16x8 b1 = *reinterpret_cast<const f16x8*>(bp + 16 * 8);
    acc[0] = __builtin_amdgcn_mfma_f32_16x16x32_f16(av, b0, acc[0], 0, 0, 0);
    acc[1] = __builtin_amdgcn_mfma_f32_16x16x32_f16(av, b1, acc[1], 0, 0, 0);
  }

  float e[2][4];
#pragma unroll
  for (int nf = 0; nf < 2; ++nf)
#pragma unroll
    for (int q = 0; q < 4; ++q) e[nf][q] = __expf(acc[nf][q]);

  float rp[4];
#pragma unroll
  for (int q = 0; q < 4; ++q) {
    rp[q] = e[0][q] + e[1][q];
#pragma unroll
    for (int msk = 1; msk < 16; msk <<= 1) rp[q] += __shfl_xor(rp[q], msk, 64);
  }
  if (lm == 0)
#pragma unroll
    for (int q = 0; q < 4; ++q) rowsum[quad * 4 + q][w] = rp[q];
  __syncthreads();

#pragma unroll
  for (int q = 0; q < 4; ++q) {
    const int row = quad * 4 + q;
    float s8 = 0.f;
#pragma unroll
    for (int w2 = 0; w2 < 8; ++w2) s8 += rowsum[row][w2];
    const float inv = 1.0f / (s8 + 1e-8f);
#pragma unroll
    for (int nf = 0; nf < 2; ++nf)
      P[(size_t)(m0 + row) * R_RULES + w * 32 + nf * 16 + lm] =
          (f16)(e[nf][q] * inv);
  }
}

// ---------------------------------------------------------------------------
// Kernel 3 v7 (rules32v2): 32x32x16 MFMA, dependency-structure fix.
// R6's rules32 was ~30us: ONE acc per wave = 129-long dependent MFMA chain
// (m119: peak needs 2-8 indep chains; 32x32 latency ~4x its 32.3cy issue).
// This version:
//  - wave tile 64 rows x 32 cols -> TWO independent acc chains per wave;
//    2 waves/SIMD -> 4 interleaved chains/SIMD: matrix issue covered.
//  - NO B staging, NO K-loop barriers: B-fragments stream L2->reg as
//    wave-contiguous 1KB bursts through an 8-deep static register ring
//    (load-use-replace, ~1000cy prefetch distance).  Cp3 per group (288KB)
//    is XCD-L2-resident via g=blockIdx&15; mh-partner duplicate hits L1.
//  - X in LDS only (70KB), single barrier.
//  - block 512thr/8 waves = 4 mq x 2 jh = 256 rows x 64 cols; grid 16x16
//    = 256 = 1 block/CU.
// Floors/CU: MFMA 6.9us, L2-B 3.5us, VALU 1.7us -> expect ~8-10us.
// Launched twice: nrep=6 -> scratch (instrumentation; shows in top-5 with
// counters), nrep=1 -> part (final path).
// ---------------------------------------------------------------------------
__global__ __launch_bounds__(512) void anfis_rules32v2(
    const float* __restrict__ X, const f16* __restrict__ P,
    const f16* __restrict__ Cp3, float* __restrict__ outp, int nrep) {
  __shared__ alignas(16) f16 Xs[256 * KPAD];   // 69632 B
  const int tid = threadIdx.x;
  const int g = blockIdx.x & 15;
  const int m0 = (blockIdx.x >> 4) * 256;
  const int w = tid >> 6, lane = tid & 63;
  const int mq = w >> 1, jh = w & 1;
  const int jl = lane & 31, rh = lane >> 5;
  union F8 { f16x8 v; f16x2 h[4]; };

  for (int rep = 0; rep < nrep; ++rep) {
    asm volatile("" ::: "memory");
    // stage X: 256 rows x 128 f32 -> f16, coalesced, + bias col
#pragma unroll
    for (int it = 0; it < 16; ++it) {
      int fi = tid + (it << 9);
      int m = fi >> 5, k4 = (fi & 31) << 2;
      float4 v = reinterpret_cast<const float4*>(X)[(size_t)(m0 + m) * 32 + (fi & 31)];
      f16x4 h = {(f16)v.x, (f16)v.y, (f16)v.z, (f16)v.w};
      *reinterpret_cast<f16x4*>(&Xs[m * KPAD + k4]) = h;
    }
    if (tid < 256) {
      f16x8 bias = {};
      bias[0] = (f16)1.0f;
      *reinterpret_cast<f16x8*>(&Xs[tid * KPAD + 128]) = bias;
    }
    F8 pf[2];
#pragma unroll
    for (int ms = 0; ms < 2; ++ms) {
      int row = m0 + mq * 64 + ms * 32 + jl;
      pf[ms].v = *reinterpret_cast<const f16x8*>(
          &P[(size_t)row * R_RULES + g * 16 + rh * 8]);
    }
    __syncthreads();   // Xs ready; only barrier in the K-path

    // per-lane B stream base: group + jh/rh/jl sub-offsets; +i*2048 per i
    const char* bp = (const char*)Cp3 + (size_t)g * (CP3_I * 2048) +
                     jh * 1024 + rh * 512 + jl * 16;
    f16x8 bbuf[8];
#pragma unroll
    for (int ii = 0; ii < 8; ++ii)
      bbuf[ii] = *reinterpret_cast<const f16x8*>(bp + (size_t)ii * 2048);

    f32x16 acc[2] = {};
    for (int ch = 0; ch < 16; ++ch) {
      f16x8 xv[2];
#pragma unroll
      for (int ms = 0; ms < 2; ++ms)
        xv[ms] = *reinterpret_cast<const f16x8*>(
            &Xs[(mq * 64 + ms * 32 + jl) * KPAD + ch * 8]);
      const char* bnext = bp + ((size_t)ch + 1) * 16384;  // ch=15 -> i=128.. (bias rows, written)
#pragma unroll
      for (int ii = 0; ii < 8; ++ii) {
        f16x8 b0 = bbuf[ii];
        bbuf[ii] = *reinterpret_cast<const f16x8*>(bnext + (size_t)ii * 2048);
#pragma unroll
        for (int ms = 0; ms < 2; ++ms) {
          f16 xs = xv[ms][ii];
          f16x2 xd = {xs, xs};
          F8 a;
          a.h[0] = pf[ms].h[0] * xd;
          a.h[1] = pf[ms].h[1] * xd;
          a.h[2] = pf[ms].h[2] * xd;
          a.h[3] = pf[ms].h[3] * xd;
          acc[ms] = __builtin_amdgcn_mfma_f32_32x32x16_f16(a.v, b0, acc[ms], 0, 0, 0);
        }
      }
    }
    // bias tail: i=128 (X==1 -> A = pf); bbuf[0] holds i=128 after ch=15
#pragma unroll
    for (int ms = 0; ms < 2; ++ms)
      acc[ms] = __builtin_amdgcn_mfma_f32_32x32x16_f16(pf[ms].v, bbuf[0], acc[ms], 0, 0, 0);

    // C/D: col = jl, row = (q&3) + 8*(q>>2) + 4*rh
#pragma unroll
    for (int ms = 0; ms < 2; ++ms)
#pragma unroll
      for (int q = 0; q < 16; ++q) {
        int r = (q & 3) + 8 * (q >> 2) + 4 * rh;
        outp[((size_t)g * N_SAMPLES + (m0 + mq * 64 + ms * 32 + r)) * O_OUT +
             jh * 32 + jl] = acc[ms][q];
      }
    __syncthreads();   // rep fence (Xs reuse)
  }
}

// ---------------------------------------------------------------------------
// Kernel 4 (unchanged): sum 16 group partials + softmax over 64 outputs.
// ---------------------------------------------------------------------------
__global__ __launch_bounds__(256) void anfis_out(
    const float* __restrict__ part, float* __restrict__ out) {
  const int n = blockIdx.x * 4 + (threadIdx.x >> 6);
  const int lane = threadIdx.x & 63;
  const size_t stride = (size_t)N_SAMPLES * O_OUT;
  const float* p0 = part + (size_t)n * O_OUT + lane;
  float v = 0.f;
#pragma unroll
  for (int gg = 0; gg < 16; ++gg) v += p0[gg * stride];
  float mx = v;
#pragma unroll
  for (int off = 32; off; off >>= 1) mx = fmaxf(mx, __shfl_xor(mx, off, 64));
  float e = __expf(v - mx);
  float s = e;
#pragma unroll
  for (int off = 32; off; off >>= 1) s += __shfl_xor(s, off, 64);
  out[(size_t)n * O_OUT + lane] = e / s;
}

extern "C" void kernel_launch(void* const* d_in, const int* in_sizes, int n_in,
                              void* d_out, int out_size, void* d_ws, size_t ws_size,
                              hipStream_t stream) {
  const float* X       = (const float*)d_in[0];
  const float* centers = (const float*)d_in[1];
  const float* sigmas  = (const float*)d_in[2];
  const float* coeffs  = (const float*)d_in[3];
  float* out = (float*)d_out;

  float* part = (float*)d_ws;                                    // 16.78 MB
  f16*   Cp3  = (f16*)(part + (size_t)NG16 * N_SAMPLES * O_OUT);
  f16*   Bext = Cp3 + (size_t)NG16 * CP3_I * 1024;               // 4.72 MB
  f16*   P    = Bext + (size_t)100 * 256 * 8;                    // 400 KB
  float* scratch = (float*)(P + (size_t)N_SAMPLES * R_RULES);    // 16.78 MB

  anfis_prep_all<<<1088 + 128, 256, 0, stream>>>(coeffs, centers, sigmas, Cp3, Bext);
  anfis_s16n<<<N_SAMPLES / 16, 512, 0, stream>>>(X, Bext, P);
  anfis_rules32v2<<<256, 512, 0, stream>>>(X, P, Cp3, scratch, 6);  // instrumented
  anfis_rules32v2<<<256, 512, 0, stream>>>(X, P, Cp3, part, 1);     // final path
  anfis_out<<<N_SAMPLES / 4, 256, 0, stream>>>(part, out);
}

// Round 8
// 107.799 us; speedup vs baseline: 2.1998x; 2.1998x over previous
//
#include <hip/hip_runtime.h>

#define N_SAMPLES 4096
#define D_IN      128
#define R_RULES   256
#define O_OUT     64
#define KPAD      136
#define NG16      16     // 16 rule-groups of 16 rules (K=16 per MFMA)
#define CP3_I     144    // padded i-slots per group in Cp3
#define NPLANES   32     // 16 groups x 2 K-halves

typedef _Float16 f16;
typedef _Float16 f16x2 __attribute__((ext_vector_type(2)));
typedef _Float16 f16x4 __attribute__((ext_vector_type(4)));
typedef _Float16 f16x8 __attribute__((ext_vector_type(8)));
typedef float    f32x4 __attribute__((ext_vector_type(4)));
typedef float    f32x16 __attribute__((ext_vector_type(16)));

// ---------------------------------------------------------------------------
// Kernel 1 (unchanged): fused prep -> Cp3 (32x32 B-fragment layout) + Bext.
// ---------------------------------------------------------------------------
__global__ __launch_bounds__(256) void anfis_prep_all(
    const float* __restrict__ coeffs, const float* __restrict__ centers,
    const float* __restrict__ sigmas, f16* __restrict__ Cp3,
    f16* __restrict__ Bext) {
  __shared__ alignas(16) f16 T[64 * 32];
  __shared__ float red[4];
  const int bid = blockIdx.x;
  const int tid = threadIdx.x;

  if (bid < 1088) {
    const int g8 = bid / 136;
    const int i = bid - g8 * 136;
    const int rg = tid & 31;
    const int jb = tid >> 5;
    if (i < 129) {
      const float* src = coeffs + ((size_t)(g8 * 32 + rg) * 129 + i) * 64 + jb * 8;
      float4 a = reinterpret_cast<const float4*>(src)[0];
      float4 b = reinterpret_cast<const float4*>(src)[1];
      T[(jb * 8 + 0) * 32 + rg] = (f16)a.x;
      T[(jb * 8 + 1) * 32 + rg] = (f16)a.y;
      T[(jb * 8 + 2) * 32 + rg] = (f16)a.z;
      T[(jb * 8 + 3) * 32 + rg] = (f16)a.w;
      T[(jb * 8 + 4) * 32 + rg] = (f16)b.x;
      T[(jb * 8 + 5) * 32 + rg] = (f16)b.y;
      T[(jb * 8 + 6) * 32 + rg] = (f16)b.z;
      T[(jb * 8 + 7) * 32 + rg] = (f16)b.w;
    } else {
#pragma unroll
      for (int q = 0; q < 8; ++q) T[(jb * 8 + q) * 32 + rg] = (f16)0.0f;
    }
    __syncthreads();
    const int j = tid >> 2, oc = tid & 3;
    const int g16 = g8 * 2 + (oc >> 1), rh = oc & 1;
    const int jh = j >> 5, jl = j & 31;
    f16x8* dst3 = reinterpret_cast<f16x8*>(Cp3);
    dst3[(((size_t)g16 * CP3_I + i) * 2 + jh) * 64 + rh * 32 + jl] =
        *reinterpret_cast<const f16x8*>(&T[j * 32 + oc * 8]);
  } else {
    const int sub = tid >> 7;
    const int d = tid & 127;
    const int r = ((bid - 1088) << 1) + sub;
    const float c = centers[(size_t)r * 128 + d];
    const float s = sigmas[(size_t)r * 128 + d];
    const float iv = 0.5f / (s * s);
    const float b1 = -iv;
    const float b2 = 2.0f * c * iv;
    f16 b1h = (f16)b1; f16 b1l = (f16)(b1 - (float)b1h);
    f16 b2h = (f16)b2; f16 b2l = (f16)(b2 - (float)b2h);
    auto put = [&](int k, f16 v) {
      Bext[((size_t)(k >> 3) * 256 + r) * 8 + (k & 7)] = v;
    };
    put(d, b1h);
    put(128 + d, b1l);
    put(256 + d, b1h);
    put(384 + d, b2h);
    put(512 + d, b2l);
    put(640 + d, b2h);
    float p = -c * c * iv;
#pragma unroll
    for (int off = 32; off; off >>= 1) p += __shfl_xor(p, off, 64);
    if ((tid & 63) == 0) red[tid >> 6] = p;
    __syncthreads();
    if (d < 30) put(770 + d, (f16)0.0f);
    if (d == 0) {
      float k2 = red[sub * 2] + red[sub * 2 + 1];
      f16 h = (f16)k2; f16 l = (f16)(k2 - (float)h);
      put(768, h);
      put(769, l);
    }
  }
}

// ---------------------------------------------------------------------------
// Kernel 2 (unchanged): strengths + normalization fused.
// ---------------------------------------------------------------------------
__global__ __launch_bounds__(512) void anfis_s16n(
    const float* __restrict__ X, const f16* __restrict__ Bext,
    f16* __restrict__ P) {
  __shared__ alignas(16) f16 Xq[16 * 512];
  __shared__ float rowsum[16][8];
  const int tid = threadIdx.x;
  const int m0 = blockIdx.x * 16;
  const int w = tid >> 6, lane = tid & 63;
  const int lm = lane & 15, quad = lane >> 4;

  if (tid < 256) {
    int m = tid >> 4, oct = tid & 15;
    const float* src = X + (size_t)(m0 + m) * 128 + oct * 8;
    float4 a = reinterpret_cast<const float4*>(src)[0];
    float4 b = reinterpret_cast<const float4*>(src)[1];
    float xs[8] = {a.x, a.y, a.z, a.w, b.x, b.y, b.z, b.w};
    f16x8 vh, vl, v2h, v2l;
#pragma unroll
    for (int q = 0; q < 8; ++q) {
      float x = xs[q];
      f16 h = (f16)x;   f16 l = (f16)(x - (float)h);
      float x2 = x * x;
      f16 h2 = (f16)x2; f16 l2 = (f16)(x2 - (float)h2);
      vh[q] = h; vl[q] = l; v2h[q] = h2; v2l[q] = l2;
    }
    f16x8* row = reinterpret_cast<f16x8*>(&Xq[m * 512]);
    int sw = m & 7;
    row[(0 * 16 + oct) ^ sw] = v2h;
    row[(1 * 16 + oct) ^ sw] = v2l;
    row[(2 * 16 + oct) ^ sw] = vh;
    row[(3 * 16 + oct) ^ sw] = vl;
  }
  __syncthreads();

  f32x4 acc[2] = {};
  const f16x8* arow = reinterpret_cast<const f16x8*>(&Xq[lm * 512]);
  const int asw = lm & 7;
  const int col0 = w * 32 + lm;

#pragma unroll
  for (int t = 0; t < 24; ++t) {
    const int seg = t >> 2;
    const int plane = (seg < 2) ? 0 : (seg == 2) ? 1 : (seg < 5) ? 2 : 3;
    const int o = t * 4 + quad;
    f16x8 av = arow[(plane * 16 + (o & 15)) ^ asw];
    const f16* bp = Bext + ((size_t)o * 256 + col0) * 8;
    f16x8 b0 = *reinterpret_cast<const f16x8*>(bp);
    f16x8 b1 = *reinterpret_cast<const f16x8*>(bp + 16 * 8);
    acc[0] = __builtin_amdgcn_mfma_f32_16x16x32_f16(av, b0, acc[0], 0, 0, 0);
    acc[1] = __builtin_amdgcn_mfma_f32_16x16x32_f16(av, b1, acc[1], 0, 0, 0);
  }
  {
    f16x8 av = {};
    if (quad == 0) { av[0] = (f16)1.0f; av[1] = (f16)1.0f; }
    const int o = 96 + quad;
    const f16* bp = Bext + ((size_t)o * 256 + col0) * 8;
    f16x8 b0 = *reinterpret_cast<const f16x8*>(bp);
    f16x8 b1 = *reinterpret_cast<const f16x8*>(bp + 16 * 8);
    acc[0] = __builtin_amdgcn_mfma_f32_16x16x32_f16(av, b0, acc[0], 0, 0, 0);
    acc[1] = __builtin_amdgcn_mfma_f32_16x16x32_f16(av, b1, acc[1], 0, 0, 0);
  }

  float e[2][4];
#pragma unroll
  for (int nf = 0; nf < 2; ++nf)
#pragma unroll
    for (int q = 0; q < 4; ++q) e[nf][q] = __expf(acc[nf][q]);

  float rp[4];
#pragma unroll
  for (int q = 0; q < 4; ++q) {
    rp[q] = e[0][q] + e[1][q];
#pragma unroll
    for (int msk = 1; msk < 16; msk <<= 1) rp[q] += __shfl_xor(rp[q], msk, 64);
  }
  if (lm == 0)
#pragma unroll
    for (int q = 0; q < 4; ++q) rowsum[quad * 4 + q][w] = rp[q];
  __syncthreads();

#pragma unroll
  for (int q = 0; q < 4; ++q) {
    const int row = quad * 4 + q;
    float s8 = 0.f;
#pragma unroll
    for (int w2 = 0; w2 < 8; ++w2) s8 += rowsum[row][w2];
    const float inv = 1.0f / (s8 + 1e-8f);
#pragma unroll
    for (int nf = 0; nf < 2; ++nf)
      P[(size_t)(m0 + row) * R_RULES + w * 32 + nf * 16 + lm] =
          (f16)(e[nf][q] * inv);
  }
}

// ---------------------------------------------------------------------------
// Kernel 3 v8 (rules32v3): R7's structure + K-SPLIT across blocks for TLP.
// R7 measured 22.5us with MfmaUtil 35.5 / VALUBusy 35.8 / Occ 20.7: three
// ~7-8us pipe loads SERIALIZED at <2 waves/SIMD.  Splitting each (m,g) tile
// into kh=0 (i 0..63) and kh=1 (i 64..128) blocks doubles resident waves to
// 16/CU = 4/SIMD at UNCHANGED per-CU L1 traffic (1.03MB), MFMA total
// (7.3us/SIMD), VALU total -> pipes overlap (m114) -> expect ~10-13us.
//  - grid 512 = 16 m x 2 kh x 16 g; 512thr/8 waves; 2 blocks/CU.
//  - LDS: X only (69.6KB x2 = 139KB/CU); single barrier; reg-ring B stream.
// ---------------------------------------------------------------------------
__global__ __launch_bounds__(512, 4) void anfis_rules32v3(
    const float* __restrict__ X, const f16* __restrict__ P,
    const f16* __restrict__ Cp3, float* __restrict__ part) {
  __shared__ alignas(16) f16 Xs[256 * KPAD];   // 69632 B
  const int tid = threadIdx.x;
  const int bid = blockIdx.x;
  const int g = bid & 15;
  const int kh = (bid >> 4) & 1;
  const int m0 = (bid >> 5) * 256;
  const int w = tid >> 6, lane = tid & 63;
  const int mq = w >> 1, jh = w & 1;
  const int jl = lane & 31, rh = lane >> 5;
  union F8 { f16x8 v; f16x2 h[4]; };

  // stage X: 256 rows x 128 f32 -> f16, coalesced, + bias col
#pragma unroll
  for (int it = 0; it < 16; ++it) {
    int fi = tid + (it << 9);
    int m = fi >> 5, k4 = (fi & 31) << 2;
    float4 v = reinterpret_cast<const float4*>(X)[(size_t)(m0 + m) * 32 + (fi & 31)];
    f16x4 h = {(f16)v.x, (f16)v.y, (f16)v.z, (f16)v.w};
    *reinterpret_cast<f16x4*>(&Xs[m * KPAD + k4]) = h;
  }
  if (tid < 256) {
    f16x8 bias = {};
    bias[0] = (f16)1.0f;
    *reinterpret_cast<f16x8*>(&Xs[tid * KPAD + 128]) = bias;
  }
  F8 pf[2];
#pragma unroll
  for (int ms = 0; ms < 2; ++ms) {
    int row = m0 + mq * 64 + ms * 32 + jl;
    pf[ms].v = *reinterpret_cast<const f16x8*>(
        &P[(size_t)row * R_RULES + g * 16 + rh * 8]);
  }
  __syncthreads();   // Xs ready; only barrier

  // per-lane B stream base for this K-half
  const char* bp = (const char*)Cp3 + (size_t)g * (CP3_I * 2048) +
                   (size_t)kh * 8 * 16384 + jh * 1024 + rh * 512 + jl * 16;
  f16x8 bbuf[8];
#pragma unroll
  for (int ii = 0; ii < 8; ++ii)
    bbuf[ii] = *reinterpret_cast<const f16x8*>(bp + (size_t)ii * 2048);

  f32x16 acc[2] = {};
  for (int c = 0; c < 8; ++c) {
    const int ch = kh * 8 + c;
    f16x8 xv[2];
#pragma unroll
    for (int ms = 0; ms < 2; ++ms)
      xv[ms] = *reinterpret_cast<const f16x8*>(
          &Xs[(mq * 64 + ms * 32 + jl) * KPAD + ch * 8]);
    const char* bnext = bp + ((size_t)c + 1) * 16384;  // kh=1,c=7 -> i=128 block
#pragma unroll
    for (int ii = 0; ii < 8; ++ii) {
      f16x8 b0 = bbuf[ii];
      bbuf[ii] = *reinterpret_cast<const f16x8*>(bnext + (size_t)ii * 2048);
#pragma unroll
      for (int ms = 0; ms < 2; ++ms) {
        f16 xs = xv[ms][ii];
        f16x2 xd = {xs, xs};
        F8 a;
        a.h[0] = pf[ms].h[0] * xd;
        a.h[1] = pf[ms].h[1] * xd;
        a.h[2] = pf[ms].h[2] * xd;
        a.h[3] = pf[ms].h[3] * xd;
        acc[ms] = __builtin_amdgcn_mfma_f32_32x32x16_f16(a.v, b0, acc[ms], 0, 0, 0);
      }
    }
  }
  if (kh == 1) {
    // bias tail: i=128 (X==1 -> A = pf); bbuf[0] holds the i=128 fragment
#pragma unroll
    for (int ms = 0; ms < 2; ++ms)
      acc[ms] = __builtin_amdgcn_mfma_f32_32x32x16_f16(pf[ms].v, bbuf[0], acc[ms], 0, 0, 0);
  }

  // C/D: col = jl, row = (q&3) + 8*(q>>2) + 4*rh ; plane = g*2+kh
#pragma unroll
  for (int ms = 0; ms < 2; ++ms)
#pragma unroll
    for (int q = 0; q < 16; ++q) {
      int r = (q & 3) + 8 * (q >> 2) + 4 * rh;
      part[((size_t)(g * 2 + kh) * N_SAMPLES + (m0 + mq * 64 + ms * 32 + r)) * O_OUT +
           jh * 32 + jl] = acc[ms][q];
    }
}

// ---------------------------------------------------------------------------
// Kernel 4: sum 32 partial planes + softmax over 64 outputs.
// ---------------------------------------------------------------------------
__global__ __launch_bounds__(256) void anfis_out(
    const float* __restrict__ part, float* __restrict__ out) {
  const int n = blockIdx.x * 4 + (threadIdx.x >> 6);
  const int lane = threadIdx.x & 63;
  const size_t stride = (size_t)N_SAMPLES * O_OUT;
  const float* p0 = part + (size_t)n * O_OUT + lane;
  float v = 0.f;
#pragma unroll
  for (int gg = 0; gg < NPLANES; ++gg) v += p0[gg * stride];
  float mx = v;
#pragma unroll
  for (int off = 32; off; off >>= 1) mx = fmaxf(mx, __shfl_xor(mx, off, 64));
  float e = __expf(v - mx);
  float s = e;
#pragma unroll
  for (int off = 32; off; off >>= 1) s += __shfl_xor(s, off, 64);
  out[(size_t)n * O_OUT + lane] = e / s;
}

extern "C" void kernel_launch(void* const* d_in, const int* in_sizes, int n_in,
                              void* d_out, int out_size, void* d_ws, size_t ws_size,
                              hipStream_t stream) {
  const float* X       = (const float*)d_in[0];
  const float* centers = (const float*)d_in[1];
  const float* sigmas  = (const float*)d_in[2];
  const float* coeffs  = (const float*)d_in[3];
  float* out = (float*)d_out;

  float* part = (float*)d_ws;                                    // 33.55 MB
  f16*   Cp3  = (f16*)(part + (size_t)NPLANES * N_SAMPLES * O_OUT);
  f16*   Bext = Cp3 + (size_t)NG16 * CP3_I * 1024;               // 4.72 MB
  f16*   P    = Bext + (size_t)100 * 256 * 8;                    // 400 KB

  anfis_prep_all<<<1088 + 128, 256, 0, stream>>>(coeffs, centers, sigmas, Cp3, Bext);
  anfis_s16n<<<N_SAMPLES / 16, 512, 0, stream>>>(X, Bext, P);
  anfis_rules32v3<<<512, 512, 0, stream>>>(X, P, Cp3, part);
  anfis_out<<<N_SAMPLES / 4, 256, 0, stream>>>(part, out);
}